// Round 1
// baseline (1394.661 us; speedup 1.0000x reference)
//
#include <hip/hip_runtime.h>

#define BB 64
#define SS 2048
#define DD 128
#define HH 128

__device__ __forceinline__ float fast_tanh(float x) {
    // tanh(x) = 1 - 2/(e^{2x}+1); exact at +-inf, ~1e-6 rel err
    float e = __expf(2.0f * x);
    return 1.0f - __fdividef(2.0f, e + 1.0f);
}

// ---------------------------------------------------------------------------
// Kernel 1: xproj = x @ Wx + b
//   x: (B*S, D) = (131072, 128), Wx = W[:128] (128x128), out: (131072, 128)
// Each block: 128 rows. Thread t: column j = t&127, row-half rh = t>>7.
// Wx column j held in 128 VGPRs; x tile staged in LDS (64KB), rows read as
// uniform (broadcast) float4 -> conflict-free.
// ---------------------------------------------------------------------------
__global__ __launch_bounds__(256, 2)
void xproj_kernel(const float* __restrict__ x, const float* __restrict__ W,
                  const float* __restrict__ bias, float* __restrict__ out) {
    __shared__ __align__(16) float xt[128 * 128];
    const int tid = threadIdx.x;
    const int j   = tid & 127;
    const int rh  = tid >> 7;
    const long row0 = (long)blockIdx.x * 128;

    // Wx column j -> registers (coalesced 256B/wave per k)
    float wx[128];
#pragma unroll
    for (int k = 0; k < 128; ++k) wx[k] = W[k * HH + j];
    const float bj = bias[j];

    // stage 128x128 x-tile into LDS, fully coalesced float4
    const float4* xg = (const float4*)(x + row0 * DD);
    float4* xl = (float4*)xt;
#pragma unroll
    for (int i = 0; i < 16; ++i) {
        const int slot = tid + i * 256;   // 4096 float4 slots
        xl[slot] = xg[slot];
    }
    __syncthreads();

    for (int r = rh; r < 128; r += 2) {
        const float4* xr = (const float4*)(xt + r * 128);
        float a0 = bj, a1 = 0.f, a2 = 0.f, a3 = 0.f;
#pragma unroll
        for (int k4 = 0; k4 < 32; ++k4) {
            const float4 v = xr[k4];    // uniform address -> LDS broadcast
            a0 = fmaf(v.x, wx[4*k4+0], a0);
            a1 = fmaf(v.y, wx[4*k4+1], a1);
            a2 = fmaf(v.z, wx[4*k4+2], a2);
            a3 = fmaf(v.w, wx[4*k4+3], a3);
        }
        out[(row0 + r) * HH + j] = (a0 + a1) + (a2 + a3);
    }
}

// ---------------------------------------------------------------------------
// Kernel 2: sequential recurrence, one block per batch (64 blocks x 256 thr).
//   h_new = tanh(xproj[b,t,:] + h @ Wh),  Wh = W[128:] (128x128)
// Thread (wave w, lane l): k-slice s=l&3 (32 k's), outputs j = w*16+(l>>2)
// and j+64. Wh fragment (64 floats) in registers. h double-buffered in LDS,
// read as broadcast float4. Partial sums reduced over 4 lanes via shfl_xor.
// xproj streamed from d_out (written by kernel 1) in 16-step LDS chunks,
// prefetched one chunk ahead; outputs overwrite xproj in place.
// ---------------------------------------------------------------------------
__global__ __launch_bounds__(256, 1)
void rnn_kernel(const float* __restrict__ W, float* __restrict__ out) {
    const int CH = 16;            // steps per chunk
    const int NC = SS / CH;       // 128 chunks

    __shared__ __align__(16) float xps[2][CH * HH]; // 2 x 8KB xproj chunks
    __shared__ __align__(16) float hb[2][HH];       // double-buffered h

    const int b    = blockIdx.x;
    const int tid  = threadIdx.x;
    const int lane = tid & 63;
    const int w    = tid >> 6;
    const int s4   = lane & 3;        // k-slice: k in [32*s4, 32*s4+32)
    const int m    = lane >> 2;       // 0..15
    const int jb   = w * 16 + m;      // output col; second col = jb+64

    // Wh fragments -> registers
    float wh0[32], wh1[32];
#pragma unroll
    for (int kk = 0; kk < 32; ++kk) {
        const float* wr = W + (long)(DD + 32 * s4 + kk) * HH;
        wh0[kk] = wr[jb];
        wh1[kk] = wr[jb + 64];
    }

    float* const xbase = out + (long)b * SS * HH;

    if (tid < 128) { hb[0][tid] = 0.f; hb[1][tid] = 0.f; }

    // stage chunk 0 (2048 floats = 512 float4, 2 per thread)
    {
        const float4* g = (const float4*)xbase;
        float4* l4 = (float4*)xps[0];
        l4[tid]       = g[tid];
        l4[tid + 256] = g[tid + 256];
    }
    __syncthreads();

    float4 pre0, pre1;
    for (int c = 0; c < NC; ++c) {
        // issue prefetch of chunk c+1 into registers (latency hidden by 16 steps)
        if (c + 1 < NC) {
            const float4* g = (const float4*)(xbase + (c + 1) * CH * HH);
            pre0 = g[tid];
            pre1 = g[tid + 256];
        }
        const float* xp = xps[c & 1];
#pragma unroll
        for (int tt = 0; tt < CH; ++tt) {
            const int t = c * CH + tt;
            const float* hcur = hb[(t + 1) & 1];   // state from step t-1
            const float4* hv = (const float4*)(hcur + 32 * s4);
            float acc0 = 0.f, acc1 = 0.f;
#pragma unroll
            for (int q = 0; q < 8; ++q) {
                const float4 hq = hv[q];           // 16-lane broadcast
                acc0 = fmaf(hq.x, wh0[4*q+0], acc0);
                acc0 = fmaf(hq.y, wh0[4*q+1], acc0);
                acc0 = fmaf(hq.z, wh0[4*q+2], acc0);
                acc0 = fmaf(hq.w, wh0[4*q+3], acc0);
                acc1 = fmaf(hq.x, wh1[4*q+0], acc1);
                acc1 = fmaf(hq.y, wh1[4*q+1], acc1);
                acc1 = fmaf(hq.z, wh1[4*q+2], acc1);
                acc1 = fmaf(hq.w, wh1[4*q+3], acc1);
            }
            // reduce over the 4 k-slices (lanes 4m..4m+3)
            acc0 += __shfl_xor(acc0, 1); acc0 += __shfl_xor(acc0, 2);
            acc1 += __shfl_xor(acc1, 1); acc1 += __shfl_xor(acc1, 2);

            if (s4 == 0) {
                const float h0 = fast_tanh(xp[tt * HH + jb]      + acc0);
                const float h1 = fast_tanh(xp[tt * HH + jb + 64] + acc1);
                float* hn = hb[t & 1];
                hn[jb]      = h0;
                hn[jb + 64] = h1;
                float* og = xbase + (long)t * HH;  // overwrite xproj in place
                og[jb]      = h0;
                og[jb + 64] = h1;
            }
            __syncthreads();   // h visible for step t+1
        }
        // commit prefetched chunk into the other buffer
        if (c + 1 < NC) {
            float4* l4 = (float4*)xps[(c + 1) & 1];
            l4[tid]       = pre0;
            l4[tid + 256] = pre1;
        }
        __syncthreads();
    }

    // final hidden state -> tail of d_out
    if (tid < 128) {
        out[(long)BB * SS * HH + b * HH + tid] = hb[(SS - 1) & 1][tid];
    }
}

extern "C" void kernel_launch(void* const* d_in, const int* in_sizes, int n_in,
                              void* d_out, int out_size, void* d_ws, size_t ws_size,
                              hipStream_t stream) {
    const float* x    = (const float*)d_in[0];
    const float* W    = (const float*)d_in[1];
    const float* bias = (const float*)d_in[2];
    float* out = (float*)d_out;

    xproj_kernel<<<dim3((BB * SS) / 128), dim3(256), 0, stream>>>(x, W, bias, out);
    rnn_kernel<<<dim3(BB), dim3(256), 0, stream>>>(W, out);
}

// Round 3
// 922.153 us; speedup vs baseline: 1.5124x; 1.5124x over previous
//
#include <hip/hip_runtime.h>

#define BB 64
#define SS 2048
#define DD 128
#define HH 128

__device__ __forceinline__ float fast_tanh(float x) {
    // tanh(x) = 1 - 2/(e^{2x}+1); exact at +-inf, ~1e-6 rel err
    float e = __expf(2.0f * x);
    return 1.0f - __fdividef(2.0f, e + 1.0f);
}

// quad-local butterfly reduce (lanes 4m..4m+3) via DPP quad_perm - VALU only,
// replaces __shfl_xor's ds_swizzle round-trips on the step critical path.
__device__ __forceinline__ float quad_reduce(float v) {
    int a = __builtin_amdgcn_update_dpp(0, __float_as_int(v), 0xB1, 0xF, 0xF, true); // [1,0,3,2] xor1
    v += __int_as_float(a);
    int c = __builtin_amdgcn_update_dpp(0, __float_as_int(v), 0x4E, 0xF, 0xF, true); // [2,3,0,1] xor2
    v += __int_as_float(c);
    return v;
}

// ---------------------------------------------------------------------------
// Kernel 1: xproj = x @ Wx + b  (register-tiled fp32 GEMM)
// Block: 128 rows x 128 cols, 256 threads, 8x8 micro-tile per thread.
// K split in 2 halves of 64: Wx-half (32KB) + x-half (32KB) in LDS = 64KB
// -> 2 blocks/CU. x tile XOR-swizzled on its float4 index so the 16 distinct
// row-addresses per ds_read spread over banks (stride 128 floats would be
// 16-way same-bank otherwise).
// ---------------------------------------------------------------------------
__global__ __launch_bounds__(256, 2)
void xproj_kernel(const float* __restrict__ x, const float* __restrict__ W,
                  const float* __restrict__ bias, float* __restrict__ out) {
    __shared__ __align__(16) float4 wxs[64 * 32];   // Wx half: [64 k][128 j]
    __shared__ __align__(16) float4 xsw[128 * 16];  // x half:  [128 r][64 k], swizzled
    const int tid = threadIdx.x;
    const int tx  = tid & 15;    // col block: j0 = tx*8
    const int ty  = tid >> 4;    // row block: r0 = ty*8
    const long row0 = (long)blockIdx.x * 128;

    float acc[8][8];
#pragma unroll
    for (int i = 0; i < 8; ++i)
#pragma unroll
        for (int j = 0; j < 8; ++j) acc[i][j] = 0.f;

    for (int kh = 0; kh < 2; ++kh) {
        // stage Wx[kh*64 .. +64][:]  (2048 float4, 8/thread, coalesced)
        {
            const float4* wg = (const float4*)(W + kh * 64 * HH);
#pragma unroll
            for (int i = 0; i < 8; ++i) wxs[tid + i * 256] = wg[tid + i * 256];
        }
        // stage x[row0..+128][kh*64 .. +64], swizzle float4-index by row-high bits
        {
#pragma unroll
            for (int i = 0; i < 8; ++i) {
                const int g  = tid + i * 256;   // 0..2047
                const int r  = g >> 4;
                const int k4 = g & 15;
                const float4 v = ((const float4*)(x + (row0 + r) * DD + kh * 64))[k4];
                xsw[r * 16 + (k4 ^ ((r >> 3) & 7))] = v;
            }
        }
        __syncthreads();

        for (int k4 = 0; k4 < 16; ++k4) {
            float4 xa[8];
#pragma unroll
            for (int i = 0; i < 8; ++i)
                xa[i] = xsw[(ty * 8 + i) * 16 + (k4 ^ (ty & 7))];
            float4 wa[4][2];
#pragma unroll
            for (int kk = 0; kk < 4; ++kk) {
                wa[kk][0] = wxs[(k4 * 4 + kk) * 32 + tx * 2];
                wa[kk][1] = wxs[(k4 * 4 + kk) * 32 + tx * 2 + 1];
            }
#pragma unroll
            for (int i = 0; i < 8; ++i) {
#pragma unroll
                for (int kk = 0; kk < 4; ++kk) {
                    const float xv = (kk == 0) ? xa[i].x : (kk == 1) ? xa[i].y
                                   : (kk == 2) ? xa[i].z : xa[i].w;
                    acc[i][0] = fmaf(xv, wa[kk][0].x, acc[i][0]);
                    acc[i][1] = fmaf(xv, wa[kk][0].y, acc[i][1]);
                    acc[i][2] = fmaf(xv, wa[kk][0].z, acc[i][2]);
                    acc[i][3] = fmaf(xv, wa[kk][0].w, acc[i][3]);
                    acc[i][4] = fmaf(xv, wa[kk][1].x, acc[i][4]);
                    acc[i][5] = fmaf(xv, wa[kk][1].y, acc[i][5]);
                    acc[i][6] = fmaf(xv, wa[kk][1].z, acc[i][6]);
                    acc[i][7] = fmaf(xv, wa[kk][1].w, acc[i][7]);
                }
            }
        }
        __syncthreads();
    }

    const float4 b0 = ((const float4*)bias)[tx * 2];
    const float4 b1 = ((const float4*)bias)[tx * 2 + 1];
#pragma unroll
    for (int i = 0; i < 8; ++i) {
        const float4 o0 = make_float4(acc[i][0] + b0.x, acc[i][1] + b0.y,
                                      acc[i][2] + b0.z, acc[i][3] + b0.w);
        const float4 o1 = make_float4(acc[i][4] + b1.x, acc[i][5] + b1.y,
                                      acc[i][6] + b1.z, acc[i][7] + b1.w);
        float4* og = (float4*)(out + (row0 + ty * 8 + i) * HH);
        og[tx * 2]     = o0;
        og[tx * 2 + 1] = o1;
    }
}

// ---------------------------------------------------------------------------
// Kernel 2: sequential recurrence, 64 blocks x 256 threads (1 block/batch).
// Changes vs R1:
//  - NO global memory ops inside the step loop: h goes to an LDS out-chunk
//    (hos), flushed once per 16 steps -> the per-barrier s_waitcnt vmcnt(0)
//    drain happens 128x instead of 2048x.
//  - h reads bank-staggered per k-slice (idx = 8*s4 + ((q+2*s4)&7)); Wh regs
//    loaded pre-rotated so register indices stay compile-time.
//  - quad reduce via DPP instead of __shfl_xor (no LDS pipe on crit path).
// ---------------------------------------------------------------------------
__global__ __launch_bounds__(256, 1)
void rnn_kernel(const float* __restrict__ W, float* __restrict__ out) {
    const int CH = 16;
    const int NC = SS / CH;

    __shared__ __align__(16) float xps[2][CH * HH];  // xproj chunks (2x8KB)
    __shared__ __align__(16) float hos[CH * HH];     // h out-chunk (8KB)
    __shared__ __align__(16) float hb[2][HH];        // double-buffered state

    const int b    = blockIdx.x;
    const int tid  = threadIdx.x;
    const int lane = tid & 63;
    const int w    = tid >> 6;
    const int s4   = lane & 3;     // k-slice: k in [32*s4, 32*s4+32)
    const int m    = lane >> 2;    // 0..15
    const int jb   = w * 16 + m;   // output col; second col = jb+64

    // Wh fragments, pre-rotated to match the staggered read order
    float wh0[32], wh1[32];
#pragma unroll
    for (int p = 0; p < 32; ++p) {
        const int q = p >> 2, u = p & 3;
        const int k = 32 * s4 + (((q + 2 * s4) & 7) << 2) + u;
        const float* wr = W + (long)(DD + k) * HH;
        wh0[p] = wr[jb];
        wh1[p] = wr[jb + 64];
    }

    float* const xbase = out + (long)b * SS * HH;

    if (tid < 128) { hb[0][tid] = 0.f; hb[1][tid] = 0.f; }

    // stage chunk 0
    {
        const float4* g = (const float4*)xbase;
        float4* l4 = (float4*)xps[0];
        l4[tid]       = g[tid];
        l4[tid + 256] = g[tid + 256];
    }
    __syncthreads();

    float4 pre0, pre1;
    for (int c = 0; c < NC; ++c) {
        if (c + 1 < NC) {   // prefetch next xproj chunk into registers
            const float4* g = (const float4*)(xbase + (c + 1) * CH * HH);
            pre0 = g[tid];
            pre1 = g[tid + 256];
        }
        const float* xp = xps[c & 1];
#pragma unroll
        for (int tt = 0; tt < CH; ++tt) {
            const int t = c * CH + tt;
            const float4* hv = (const float4*)hb[(t + 1) & 1];
            float acc0 = 0.f, acc1 = 0.f;
#pragma unroll
            for (int q = 0; q < 8; ++q) {
                const float4 hq = hv[8 * s4 + ((q + 2 * s4) & 7)]; // bank-staggered
                acc0 = fmaf(hq.x, wh0[4*q+0], acc0);
                acc0 = fmaf(hq.y, wh0[4*q+1], acc0);
                acc0 = fmaf(hq.z, wh0[4*q+2], acc0);
                acc0 = fmaf(hq.w, wh0[4*q+3], acc0);
                acc1 = fmaf(hq.x, wh1[4*q+0], acc1);
                acc1 = fmaf(hq.y, wh1[4*q+1], acc1);
                acc1 = fmaf(hq.z, wh1[4*q+2], acc1);
                acc1 = fmaf(hq.w, wh1[4*q+3], acc1);
            }
            acc0 = quad_reduce(acc0);
            acc1 = quad_reduce(acc1);

            if (s4 == 0) {
                const float h0 = fast_tanh(xp[tt * HH + jb]      + acc0);
                const float h1 = fast_tanh(xp[tt * HH + jb + 64] + acc1);
                float* hn = hb[t & 1];
                hn[jb]      = h0;
                hn[jb + 64] = h1;
                hos[tt * HH + jb]      = h0;   // LDS, not global!
                hos[tt * HH + jb + 64] = h1;
            }
            __syncthreads();   // lgkm-only drain (no vmem in flight)
        }
        // flush the h chunk to global (overwrites consumed xproj in place)
        {
            float4* hg = (float4*)(xbase + c * CH * HH);
            const float4* hl = (const float4*)hos;
            hg[tid]       = hl[tid];
            hg[tid + 256] = hl[tid + 256];
        }
        if (c + 1 < NC) {   // commit prefetched chunk
            float4* l4 = (float4*)xps[(c + 1) & 1];
            l4[tid]       = pre0;
            l4[tid + 256] = pre1;
        }
        __syncthreads();
    }

    // final hidden state
    if (tid < 128) {
        out[(long)BB * SS * HH + b * HH + tid] = hb[1][tid];
    }
}

extern "C" void kernel_launch(void* const* d_in, const int* in_sizes, int n_in,
                              void* d_out, int out_size, void* d_ws, size_t ws_size,
                              hipStream_t stream) {
    const float* x    = (const float*)d_in[0];
    const float* W    = (const float*)d_in[1];
    const float* bias = (const float*)d_in[2];
    float* out = (float*)d_out;

    xproj_kernel<<<dim3((BB * SS) / 128), dim3(256), 0, stream>>>(x, W, bias, out);
    rnn_kernel<<<dim3(BB), dim3(256), 0, stream>>>(W, out);
}